// Round 3
// baseline (121.876 us; speedup 1.0000x reference)
//
#include <hip/hip_runtime.h>
#include <stdint.h>

// PostProcessor3D: threshold(>0.9) + 5x5x5 stride-1 maxpool + strict-local-max
// mask on [64,512,512] fp32.
//
// R14: ZERO-BARRIER wave-independent structure. R11/R13 post-mortem: both
// land ~45 us with no pipe >42% -- the invariant is the per-slice
// vmcnt+s_barrier convoy (4 waves lockstep, block gated by slowest DMA).
// R12 proved high residency lifts realized BW; R13 proved DMA staging is
// traffic-neutral and register-lean. Combine: make every WAVE independent.
//  (a) Each wave owns a W64 x H4 output band; stages its own 8 halo'd rows
//      (144 quads + 48 trash -> 3 DMA slots/lane) into a PRIVATE
//      double-buffered LDS region. No inter-wave sharing => NO s_barrier
//      anywhere. Intra-wave RAW (DMA->ds_read) ordered by counted vmcnt;
//      ds_read->reuse ordered by compiler lgkmcnt; WAR safe (reads of
//      buf[t&1] complete before iter t+1 issues DMA into it).
//  (b) 6 blocks/CU (24.6 KB LDS) x 4 waves = 24 independent latency-hiding
//      agents per CU, each with dist-1 DMA prefetch.
//  (c) H-halo staging redundancy (8 rows per 4) is L1/L2-absorbed:
//      y-neighbor blocks differ by bid 8, z-neighbors by 256 -> same XCD.
//  (d) vmcnt schedule (fully unrolled, loads for slice t issued at iter
//      t-1): ops-after = 3 next-slice loads + (t>=5 ? 1 store : 0);
//      t=0..4 -> vmcnt(3), t=5..10 -> vmcnt(4), t=11 -> vmcnt(1).
//  (e) Clamp-replicate (R13): max over edge-replicated rows/slices == max
//      over valid window; every lane always issues 3 uniform DMA loads.
//      True W-edge handled by zeroing halo taps (center >0.9 > 0).
//
// Tile: wave W64 x H4, block = 4 waves (H16), DCHUNK=8
//       -> grid 8 x 32 x 8 = 2048 blocks, 256 thr.

#define THRESH 0.9f

constexpr int D = 64, H = 512, W = 512;
constexpr int HW = H * W;
constexpr int TW = 64;                    // per-wave tile width (floats)
constexpr int WH = 4;                     // per-wave tile height (rows)
constexpr int NWAVES = 4;                 // waves per block (band = 16 rows)
constexpr int DCHUNK = 8;                 // depth outputs per block
constexpr int HALO = 2;
constexpr int SROWS = WH + 2 * HALO;      // 8 staged rows per wave
constexpr int RAWQ = TW / 4 + 2;          // 18 quads/row
constexpr int NQ = SROWS * RAWQ;          // 144 real quads
constexpr int SLOTS = 192;                // 3 x 64 (DMA lane rigidity)
constexpr int NS = DCHUNK + 2 * HALO;     // 12 slices per block

typedef float floatx4 __attribute__((ext_vector_type(4)));
using gu32p = const __attribute__((address_space(1))) uint32_t*;
using lu32p = __attribute__((address_space(3))) uint32_t*;

__device__ __forceinline__ float4 max4(float4 a, float4 b) {
    return make_float4(fmaxf(a.x, b.x), fmaxf(a.y, b.y),
                       fmaxf(a.z, b.z), fmaxf(a.w, b.w));
}

// 5-tap sliding max for one quad. b = own (f4..f7), f2,f3 = left neighbor's
// .z,.w; f8,f9 = right neighbor's .x,.y. out[j] = max over [4c+j-2, 4c+j+2].
__device__ __forceinline__ float4 wmax5s(float f2, float f3, float4 b,
                                         float f8, float f9) {
    const float f4 = b.x, f5 = b.y, f6 = b.z, f7 = b.w;
    const float m45 = fmaxf(f4, f5);
    const float m56 = fmaxf(f5, f6);
    const float m345 = fmaxf(f3, m45);
    const float m456 = fmaxf(f4, m56);
    const float m567 = fmaxf(m56, f7);
    const float m678 = fmaxf(fmaxf(f6, f7), f8);
    float4 r;
    r.x = fmaxf(fmaxf(f2, f6), m345);
    r.y = fmaxf(fmaxf(f3, f7), m456);
    r.z = fmaxf(fmaxf(f4, f8), m567);
    r.w = fmaxf(fmaxf(f5, f9), m678);
    return r;
}

__global__ __launch_bounds__(256)
__attribute__((amdgpu_num_vgpr(64)))
void peak3d_kernel(const float* __restrict__ in, float* __restrict__ out) {
    __shared__ float4 raw[NWAVES][2][SLOTS];   // 4 x 2 x 192 x 16 = 24576 B

    const int tid = threadIdx.y * 16 + threadIdx.x;
    const int wid = tid >> 6;             // wave id 0..3
    const int lane = tid & 63;
    const int tx = lane & 15;             // quad col 0..15
    const int tyw = lane >> 4;            // row in band 0..3

    const int w0 = blockIdx.x * TW;
    const int hb = blockIdx.y * (WH * NWAVES) + wid * WH;  // band top row
    const int d0 = blockIdx.z * DCHUNK;

    // 3 per-lane staging source offsets (clamp-replicate; trash -> slot 143).
    int off0, off1, off2;
#pragma unroll
    for (int i = 0; i < 3; ++i) {
        int s = min(i * 64 + lane, NQ - 1);
        const int r = s / RAWQ, c = s % RAWQ;
        const int gh = min(max(hb + r - HALO, 0), H - 1);
        const int gw = min(max(w0 + 4 * c - 4, 0), W - 4);
        const int o = gh * W + gw;
        if (i == 0) off0 = o; else if (i == 1) off1 = o; else off2 = o;
    }

    // Consume-phase indices (per wave-private region).
    const int rbase = tyw * RAWQ + tx + 1;         // + rr*RAWQ, rr=0..4
    const bool isL = (tx == 0), isR = (tx == 15);
    const bool edgeW = (isL && w0 == 0) || (isR && w0 == W - TW);
    // halo float2 index: left reads .z,.w of quad col 0; right .x,.y of 17.
    const int hbase = (tyw * RAWQ + (isL ? 0 : RAWQ - 1)) * 2 + (isL ? 1 : 0);

    const float4 zero4 = make_float4(0.f, 0.f, 0.f, 0.f);
    float4 win[5];                        // HW-max ring, depth 5 (D window)
    float4 cen[2];                        // raw center ring, depth 2
#pragma unroll
    for (int k = 0; k < 5; ++k) win[k] = zero4;
    cen[0] = zero4; cen[1] = zero4;

    // Issue 3 DMA loads for slice t (clamped) into wave-private raw[wid][t&1].
    // LDS dest must be wave-uniform (HW adds lane*16); global src is per-lane.
    auto stage = [&](int t) {
        const int dd = min(max(d0 - HALO + t, 0), D - 1);
        const float* sp = in + dd * HW;
        float4* ldsb = &raw[wid][t & 1][0];
        __builtin_amdgcn_global_load_lds((gu32p)(sp + off0),
                                         (lu32p)(ldsb + 0),   16, 0, 0);
        __builtin_amdgcn_global_load_lds((gu32p)(sp + off1),
                                         (lu32p)(ldsb + 64),  16, 0, 0);
        __builtin_amdgcn_global_load_lds((gu32p)(sp + off2),
                                         (lu32p)(ldsb + 128), 16, 0, 0);
    };

    stage(0);                             // prologue: slice 0 in flight

#pragma unroll
    for (int t = 0; t < NS; ++t) {        // fully unrolled: t constant
        const int buf = t & 1;

        if (t + 1 < NS) stage(t + 1);     // dist-1 DMA prefetch

        // ---- wait: slice-t DMA retired (per-wave, NO barrier) ----
        // ops issued after slice-t loads: 3 next-slice loads (t<=10)
        // + 1 store (t>=5).
        if (t == NS - 1) {
            asm volatile("s_waitcnt vmcnt(1)" ::: "memory");
        } else if (t >= 5) {
            asm volatile("s_waitcnt vmcnt(4)" ::: "memory");
        } else {
            asm volatile("s_waitcnt vmcnt(3)" ::: "memory");
        }

        // ---- consume: H-max (5 rows) from wave-private LDS ----
        const float4* bp = &raw[wid][buf][0];
        const float4 r0q = bp[rbase + 0 * RAWQ];
        const float4 r1q = bp[rbase + 1 * RAWQ];
        const float4 r2q = bp[rbase + 2 * RAWQ];   // center row (raw)
        const float4 r3q = bp[rbase + 3 * RAWQ];
        const float4 r4q = bp[rbase + 4 * RAWQ];
        const float4 hv = max4(max4(max4(r0q, r1q), max4(r3q, r4q)), r2q);

        // ---- halo H-max: edge lanes only, after hv fold ----
        float2 h = make_float2(0.f, 0.f);
        if (isL || isR) {
            const float2* hp = reinterpret_cast<const float2*>(bp);
            const float2 e0 = hp[hbase + 0 * RAWQ * 2];
            const float2 e1 = hp[hbase + 1 * RAWQ * 2];
            const float2 e2 = hp[hbase + 2 * RAWQ * 2];
            const float2 e3 = hp[hbase + 3 * RAWQ * 2];
            const float2 e4 = hp[hbase + 4 * RAWQ * 2];
            h.x = fmaxf(fmaxf(fmaxf(e0.x, e1.x), fmaxf(e3.x, e4.x)), e2.x);
            h.y = fmaxf(fmaxf(fmaxf(e0.y, e1.y), fmaxf(e3.y, e4.y)), e2.y);
            if (edgeW) { h.x = 0.f; h.y = 0.f; }   // true OOB in W: pad 0
        }

        // ---- W-max via shuffles on H-maxed quads (intra-wave) ----
        float f2 = __shfl_up(hv.z, 1);
        float f3 = __shfl_up(hv.w, 1);
        float f8 = __shfl_down(hv.x, 1);
        float f9 = __shfl_down(hv.y, 1);
        if (isL) { f2 = h.x; f3 = h.y; }
        if (isR) { f8 = h.x; f9 = h.y; }

        win[t % 5] = wmax5s(f2, f3, hv, f8, f9);   // HW-max, slice t

        // ---- D-max + strict-local-max + store (center = slice t-2) ----
        if (t >= 4) {
            const int dout = d0 + (t - 4);
            const float4 mp = max4(max4(max4(win[0], win[1]),
                                        max4(win[2], win[3])), win[4]);
            const float4 c = cen[t & 1];           // written at iter t-2
            floatx4 res;
            res.x = (c.x > THRESH && mp.x == c.x) ? c.x : 0.f;
            res.y = (c.y > THRESH && mp.y == c.y) ? c.y : 0.f;
            res.z = (c.z > THRESH && mp.z == c.z) ? c.z : 0.f;
            res.w = (c.w > THRESH && mp.w == c.w) ? c.w : 0.f;
            floatx4* op = reinterpret_cast<floatx4*>(
                out + (size_t)(dout * HW + (hb + tyw) * W + (w0 + 4 * tx)));
            __builtin_nontemporal_store(res, op);
        }
        cen[t & 1] = r2q;                          // write AFTER read above
    }
}

extern "C" void kernel_launch(void* const* d_in, const int* in_sizes, int n_in,
                              void* d_out, int out_size, void* d_ws, size_t ws_size,
                              hipStream_t stream) {
    const float* in = (const float*)d_in[0];
    float* out = (float*)d_out;
    dim3 grid(W / TW, H / (WH * NWAVES), D / DCHUNK);  // 8 x 32 x 8 = 2048
    dim3 block(16, 16, 1);
    hipLaunchKernelGGL(peak3d_kernel, grid, block, 0, stream, in, out);
}